// Round 1
// baseline (367.414 us; speedup 1.0000x reference)
//
#include <hip/hip_runtime.h>
#include <math.h>
#include <float.h>

// Problem dims (fixed by reference setup_inputs)
#define DDIM 1024   // D
#define PDIM 32     // pattern_dim
#define NPAT 256    // n_patterns
#define TOPK 4
#define BLOCK 256

// One block per token. Stages:
//  1. h[32]   = x . hasher_w[p,:]          (8 lanes per component)
//  2. sim[256]= h . keys[n,:]              (1 thread per pattern)
//  3. top-4 (block argmax x4, tie -> lower index, matching jax.lax.top_k)
//  4. softmax over the 4 values (thread 0)
//  5. for k in 0..3: proj = silu(x @ vd[p]); oacc += w_k * (proj @ vu[p])
//  6. out = x + scale * oacc
__global__ __launch_bounds__(BLOCK) void pattern_layer_kernel(
    const float* __restrict__ x,
    const float* __restrict__ hasher_w,   // [PDIM, DDIM]
    const float* __restrict__ keys,       // [NPAT, PDIM]
    const float* __restrict__ vd,         // [NPAT, DDIM, PDIM]
    const float* __restrict__ vu,         // [NPAT, PDIM, DDIM]
    const float* __restrict__ scale_p,    // [1]
    float* __restrict__ out)              // [ntok, DDIM]
{
    __shared__ float4 x4_s[DDIM / 4];     // 4 KB
    __shared__ float4 h4_s[PDIM / 4];
    __shared__ float4 red4[BLOCK];        // 4 KB partial sums
    __shared__ float  proj_s[PDIM];
    __shared__ float  wk_s[TOPK];
    __shared__ int    idx_s[TOPK];
    __shared__ float  wred_v[4];
    __shared__ int    wred_i[4];

    float* x_s = (float*)x4_s;
    float* h_s = (float*)h4_s;
    float* red = (float*)red4;

    const int t   = blockIdx.x;           // token index
    const int tid = threadIdx.x;

    // ---- load x row (coalesced float4; 256 threads * 4 = 1024)
    const float4 xv = ((const float4*)(x + (size_t)t * DDIM))[tid];
    x4_s[tid] = xv;
    __syncthreads();

    // ---- h[p] = sum_d x[d] * hasher_w[p*D + d]; 8 lanes per p
    {
        const int p   = tid >> 3;         // 0..31
        const int seg = tid & 7;          // 0..7 (128 d's each)
        const float4* wrow = (const float4*)(hasher_w + p * DDIM + seg * 128);
        const float4* xs   = (const float4*)(x_s + seg * 128);
        float acc = 0.f;
        #pragma unroll
        for (int i = 0; i < 32; ++i) {
            float4 w4 = wrow[i];
            float4 a4 = xs[i];
            acc = fmaf(w4.x, a4.x, acc);
            acc = fmaf(w4.y, a4.y, acc);
            acc = fmaf(w4.z, a4.z, acc);
            acc = fmaf(w4.w, a4.w, acc);
        }
        // reduce the 8 contiguous lanes of this p
        acc += __shfl_down(acc, 4, 8);
        acc += __shfl_down(acc, 2, 8);
        acc += __shfl_down(acc, 1, 8);
        if (seg == 0) h_s[p] = acc;
    }
    __syncthreads();

    // ---- sim[n] = h . keys[n,:], one thread per pattern
    float myv;
    {
        const float4* krow = (const float4*)(keys + tid * PDIM);
        float acc = 0.f;
        #pragma unroll
        for (int i = 0; i < 8; ++i) {
            float4 k4 = krow[i];
            float4 hh = h4_s[i];
            acc = fmaf(k4.x, hh.x, acc);
            acc = fmaf(k4.y, hh.y, acc);
            acc = fmaf(k4.z, hh.z, acc);
            acc = fmaf(k4.w, hh.w, acc);
        }
        myv = acc;
    }

    // hoist this thread's x slice to registers for the proj loops
    const int g   = tid & 7;              // pp group: components g*4..g*4+3
    const int seg = tid >> 3;             // 0..31, d range seg*32..seg*32+31
    float4 xr[8];
    #pragma unroll
    for (int i4 = 0; i4 < 8; ++i4) xr[i4] = x4_s[seg * 8 + i4];

    // ---- top-4 (max value, tie -> lower index)
    for (int r = 0; r < TOPK; ++r) {
        float v = myv;
        int   i = tid;
        #pragma unroll
        for (int off = 32; off > 0; off >>= 1) {
            float ov = __shfl_xor(v, off, 64);
            int   oi = __shfl_xor(i, off, 64);
            if (ov > v || (ov == v && oi < i)) { v = ov; i = oi; }
        }
        const int w = tid >> 6;
        if ((tid & 63) == 0) { wred_v[w] = v; wred_i[w] = i; }
        __syncthreads();
        if (tid == 0) {
            float bv = wred_v[0]; int bi = wred_i[0];
            #pragma unroll
            for (int j = 1; j < 4; ++j) {
                if (wred_v[j] > bv || (wred_v[j] == bv && wred_i[j] < bi)) {
                    bv = wred_v[j]; bi = wred_i[j];
                }
            }
            idx_s[r] = bi;
            wk_s[r]  = bv;   // raw top value for now
        }
        __syncthreads();
        if (tid == idx_s[r]) myv = -FLT_MAX;   // remove from next rounds
    }

    // ---- softmax over the 4 top values
    if (tid == 0) {
        float m = wk_s[0];
        #pragma unroll
        for (int j = 1; j < TOPK; ++j) m = fmaxf(m, wk_s[j]);
        float s = 0.f, e[TOPK];
        #pragma unroll
        for (int j = 0; j < TOPK; ++j) { e[j] = expf(wk_s[j] - m); s += e[j]; }
        #pragma unroll
        for (int j = 0; j < TOPK; ++j) wk_s[j] = e[j] / s;
    }
    __syncthreads();

    const float sc = scale_p[0];
    float4 oacc = make_float4(0.f, 0.f, 0.f, 0.f);

    for (int k = 0; k < TOPK; ++k) {
        const int p = idx_s[k];
        const float* vdp = vd + (size_t)p * DDIM * PDIM;
        const float* vup = vu + (size_t)p * PDIM * DDIM;

        // proj partials: this thread covers components g*4..g*4+3 over d in [seg*32, seg*32+32)
        {
            const float* basep = vdp + g * 4;
            float4 a = make_float4(0.f, 0.f, 0.f, 0.f);
            #pragma unroll
            for (int i4 = 0; i4 < 8; ++i4) {
                const float4 xd = xr[i4];
                const float* b2 = basep + (size_t)(seg * 32 + i4 * 4) * PDIM;
                float4 v0 = *(const float4*)(b2);
                float4 v1 = *(const float4*)(b2 + PDIM);
                float4 v2 = *(const float4*)(b2 + 2 * PDIM);
                float4 v3 = *(const float4*)(b2 + 3 * PDIM);
                a.x = fmaf(xd.x, v0.x, a.x); a.y = fmaf(xd.x, v0.y, a.y);
                a.z = fmaf(xd.x, v0.z, a.z); a.w = fmaf(xd.x, v0.w, a.w);
                a.x = fmaf(xd.y, v1.x, a.x); a.y = fmaf(xd.y, v1.y, a.y);
                a.z = fmaf(xd.y, v1.z, a.z); a.w = fmaf(xd.y, v1.w, a.w);
                a.x = fmaf(xd.z, v2.x, a.x); a.y = fmaf(xd.z, v2.y, a.y);
                a.z = fmaf(xd.z, v2.z, a.z); a.w = fmaf(xd.z, v2.w, a.w);
                a.x = fmaf(xd.w, v3.x, a.x); a.y = fmaf(xd.w, v3.y, a.y);
                a.z = fmaf(xd.w, v3.z, a.z); a.w = fmaf(xd.w, v3.w, a.w);
            }
            red4[tid] = a;
        }
        __syncthreads();

        // reduce 32 seg-partials per component, apply silu
        if (tid < PDIM) {
            const int gg = tid >> 2, cc = tid & 3;
            float s = 0.f;
            #pragma unroll 8
            for (int sg = 0; sg < 32; ++sg) s += red[(sg * 8 + gg) * 4 + cc];
            proj_s[tid] = s / (1.f + expf(-s));     // silu
        }
        __syncthreads();

        // o[d] accumulation: perfectly coalesced float4 column reads of vu
        {
            float4 l4 = make_float4(0.f, 0.f, 0.f, 0.f);
            const float4* col = (const float4*)vup + tid;   // vu[p][pp*D + tid*4]
            #pragma unroll
            for (int pp = 0; pp < PDIM; ++pp) {
                float4 v4 = col[pp * (DDIM / 4)];
                const float pj = proj_s[pp];
                l4.x = fmaf(pj, v4.x, l4.x);
                l4.y = fmaf(pj, v4.y, l4.y);
                l4.z = fmaf(pj, v4.z, l4.z);
                l4.w = fmaf(pj, v4.w, l4.w);
            }
            const float wkk = wk_s[k];
            oacc.x = fmaf(wkk, l4.x, oacc.x);
            oacc.y = fmaf(wkk, l4.y, oacc.y);
            oacc.z = fmaf(wkk, l4.z, oacc.z);
            oacc.w = fmaf(wkk, l4.w, oacc.w);
        }
        __syncthreads();   // red4/proj_s reused next k
    }

    // ---- residual + scale, coalesced store
    float4 r4;
    r4.x = fmaf(oacc.x, sc, xv.x);
    r4.y = fmaf(oacc.y, sc, xv.y);
    r4.z = fmaf(oacc.z, sc, xv.z);
    r4.w = fmaf(oacc.w, sc, xv.w);
    ((float4*)(out + (size_t)t * DDIM))[tid] = r4;
}

extern "C" void kernel_launch(void* const* d_in, const int* in_sizes, int n_in,
                              void* d_out, int out_size, void* d_ws, size_t ws_size,
                              hipStream_t stream) {
    const float* x        = (const float*)d_in[0];
    const float* hasher_w = (const float*)d_in[1];
    const float* keys     = (const float*)d_in[2];
    const float* vd       = (const float*)d_in[3];
    const float* vu       = (const float*)d_in[4];
    const float* scale    = (const float*)d_in[5];
    float* out = (float*)d_out;

    const int ntok = in_sizes[0] / DDIM;   // B*T = 2048

    hipLaunchKernelGGL(pattern_layer_kernel, dim3(ntok), dim3(BLOCK), 0, stream,
                       x, hasher_w, keys, vd, vu, scale, out);
}

// Round 2
// 275.024 us; speedup vs baseline: 1.3359x; 1.3359x over previous
//
#include <hip/hip_runtime.h>
#include <math.h>
#include <float.h>

#define DDIM 1024   // D
#define PDIM 32     // pattern_dim
#define NPAT 256    // n_patterns
#define TOPK 4
#define BLOCK 256
#define GTOK 16     // tokens processed per matrix sweep
#define CHUNKS 2    // blocks per pattern in main kernel
#define XSS (DDIM + DDIM / 32)   // 1056: +1 float pad per 32 -> seg stride 33 banks

// ---------------------------------------------------------------------------
// K-zero: zero the per-pattern counters (ws is poisoned 0xAA before each call)
__global__ void zero_cnt_kernel(int* __restrict__ cnt) {
    cnt[threadIdx.x] = 0;
}

// ---------------------------------------------------------------------------
// K0: routing — per token: h = x@W^T, sim = h@K^T, top-4 (tie->lower idx),
// softmax weights. Writes tki/tkw and bumps per-pattern counts.
// (verbatim from the R1 kernel that validated with absmax 0.0)
__global__ __launch_bounds__(BLOCK) void route_kernel(
    const float* __restrict__ x,
    const float* __restrict__ hasher_w,   // [PDIM, DDIM]
    const float* __restrict__ keys,       // [NPAT, PDIM]
    int*   __restrict__ tki,              // [ntok, TOPK]
    float* __restrict__ tkw,              // [ntok, TOPK]
    int*   __restrict__ cnt)              // [NPAT]
{
    __shared__ float4 x4_s[DDIM / 4];
    __shared__ float4 h4_s[PDIM / 4];
    __shared__ float  wk_s[TOPK];
    __shared__ int    idx_s[TOPK];
    __shared__ float  wred_v[4];
    __shared__ int    wred_i[4];

    float* x_s = (float*)x4_s;
    float* h_s = (float*)h4_s;

    const int t   = blockIdx.x;
    const int tid = threadIdx.x;

    x4_s[tid] = ((const float4*)(x + (size_t)t * DDIM))[tid];
    __syncthreads();

    {   // h[p], 8 lanes per p
        const int p   = tid >> 3;
        const int seg = tid & 7;
        const float4* wrow = (const float4*)(hasher_w + p * DDIM + seg * 128);
        const float4* xs   = (const float4*)(x_s + seg * 128);
        float acc = 0.f;
        #pragma unroll
        for (int i = 0; i < 32; ++i) {
            float4 w4 = wrow[i];
            float4 a4 = xs[i];
            acc = fmaf(w4.x, a4.x, acc);
            acc = fmaf(w4.y, a4.y, acc);
            acc = fmaf(w4.z, a4.z, acc);
            acc = fmaf(w4.w, a4.w, acc);
        }
        acc += __shfl_down(acc, 4, 8);
        acc += __shfl_down(acc, 2, 8);
        acc += __shfl_down(acc, 1, 8);
        if (seg == 0) h_s[p] = acc;
    }
    __syncthreads();

    float myv;
    {   // sim[n], one thread per pattern
        const float4* krow = (const float4*)(keys + tid * PDIM);
        float acc = 0.f;
        #pragma unroll
        for (int i = 0; i < 8; ++i) {
            float4 k4 = krow[i];
            float4 hh = h4_s[i];
            acc = fmaf(k4.x, hh.x, acc);
            acc = fmaf(k4.y, hh.y, acc);
            acc = fmaf(k4.z, hh.z, acc);
            acc = fmaf(k4.w, hh.w, acc);
        }
        myv = acc;
    }

    for (int r = 0; r < TOPK; ++r) {
        float v = myv;
        int   i = tid;
        #pragma unroll
        for (int off = 32; off > 0; off >>= 1) {
            float ov = __shfl_xor(v, off, 64);
            int   oi = __shfl_xor(i, off, 64);
            if (ov > v || (ov == v && oi < i)) { v = ov; i = oi; }
        }
        const int w = tid >> 6;
        if ((tid & 63) == 0) { wred_v[w] = v; wred_i[w] = i; }
        __syncthreads();
        if (tid == 0) {
            float bv = wred_v[0]; int bi = wred_i[0];
            #pragma unroll
            for (int j = 1; j < 4; ++j) {
                if (wred_v[j] > bv || (wred_v[j] == bv && wred_i[j] < bi)) {
                    bv = wred_v[j]; bi = wred_i[j];
                }
            }
            idx_s[r] = bi;
            wk_s[r]  = bv;
        }
        __syncthreads();
        if (tid == idx_s[r]) myv = -FLT_MAX;
    }

    if (tid == 0) {
        float m = wk_s[0];
        #pragma unroll
        for (int j = 1; j < TOPK; ++j) m = fmaxf(m, wk_s[j]);
        float s = 0.f, e[TOPK];
        #pragma unroll
        for (int j = 0; j < TOPK; ++j) { e[j] = expf(wk_s[j] - m); s += e[j]; }
        #pragma unroll
        for (int j = 0; j < TOPK; ++j) {
            const float wj = e[j] / s;
            tki[t * TOPK + j] = idx_s[j];
            tkw[t * TOPK + j] = wj;
            atomicAdd(&cnt[idx_s[j]], 1);
        }
    }
}

// ---------------------------------------------------------------------------
// K1: exclusive scan of 256 counts -> offs[257]; cursor = exclusive prefix
__global__ __launch_bounds__(NPAT) void scan_kernel(
    const int* __restrict__ cnt, int* __restrict__ offs, int* __restrict__ cursor)
{
    __shared__ int s[NPAT];
    const int tid = threadIdx.x;
    const int v = cnt[tid];
    s[tid] = v;
    __syncthreads();
    for (int off = 1; off < NPAT; off <<= 1) {
        int t = 0;
        if (tid >= off) t = s[tid - off];
        __syncthreads();
        s[tid] += t;
        __syncthreads();
    }
    offs[tid + 1] = s[tid];
    cursor[tid]   = s[tid] - v;
    if (tid == 0) offs[0] = 0;
}

// ---------------------------------------------------------------------------
// K2: fill CSR entry lists. entry slot j gets (token, weight*scale); slotof
// records where each (t,k) landed so the combine pass can gather.
__global__ void fill_kernel(
    const int* __restrict__ tki, const float* __restrict__ tkw,
    const float* __restrict__ scale_p, int* __restrict__ cursor,
    int* __restrict__ etok, float* __restrict__ ew, int* __restrict__ slotof,
    int nent)
{
    const int e = blockIdx.x * blockDim.x + threadIdx.x;
    if (e >= nent) return;
    const int p = tki[e];
    const int slot = atomicAdd(&cursor[p], 1);
    etok[slot]   = e >> 2;                  // token index
    ew[slot]     = tkw[e] * scale_p[0];     // fold softmax weight * scale
    slotof[e]    = slot;
}

// ---------------------------------------------------------------------------
// K3: pattern-major grouped GEMM. Block = (pattern p, chunk c). Processes its
// strided sublist of p's tokens in groups of GTOK, reading vd[p]/vu[p] once
// per group. MODE 0: store weighted contribution rows to contrib[slot].
// MODE 1: atomicAdd into out (pre-initialized to x).
template <int MODE>
__global__ __launch_bounds__(BLOCK) void pattern_gemm_kernel(
    const float* __restrict__ x,
    const float* __restrict__ vd,          // [NPAT, DDIM, PDIM]
    const float* __restrict__ vu,          // [NPAT, PDIM, DDIM]
    const int* __restrict__ offs,
    const int* __restrict__ etok,
    const float* __restrict__ ew,
    float* __restrict__ dst,               // contrib (MODE 0) or out (MODE 1)
    int nent)
{
    __shared__ float xs[GTOK * XSS];       // 67.6 KB padded x rows
    __shared__ float red[4][8][68];        // wave partials, 68-pad kills bank conflicts
    __shared__ float projT[PDIM][GTOK];    // silu(x@vd) * w, transposed
    __shared__ int   gt[GTOK];
    __shared__ float gw[GTOK];
    __shared__ int   gs[GTOK];

    const int p   = blockIdx.x >> 1;
    const int c   = blockIdx.x & 1;
    const int tid = threadIdx.x;
    const int off0 = offs[p];
    const int n    = offs[p + 1] - off0;
    const int cc   = (n > c) ? ((n - c + 1) >> 1) : 0;
    if (cc == 0) return;

    const float* vdp = vd + (size_t)p * DDIM * PDIM;
    const float* vup = vu + (size_t)p * PDIM * DDIM;

    for (int gbase = 0; gbase < cc; gbase += GTOK) {
        const int gv = min(GTOK, cc - gbase);

        if (tid < GTOK) {
            int tok, slot; float w;
            if (tid < gv) {
                const int j = off0 + c + CHUNKS * (gbase + tid);
                tok = etok[j]; w = ew[j]; slot = j;
            } else {
                tok = etok[off0 + c]; w = 0.f; slot = nent;   // dummy row
            }
            gt[tid] = tok; gw[tid] = w; gs[tid] = slot;
        }
        __syncthreads();

        // stage GTOK x rows into padded LDS
        #pragma unroll
        for (int g = 0; g < GTOK; ++g) {
            const float4 xv = ((const float4*)(x + (size_t)gt[g] * DDIM))[tid];
            const int d = tid * 4;
            *(float4*)&xs[g * XSS + d + (d >> 5)] = xv;
        }
        __syncthreads();

        // ---- phase A: proj[g][pp] = x[g] . vd[:,pp]
        const int pp4 = tid & 7;     // pp quad: pp4*4..pp4*4+3
        const int seg = tid >> 3;    // d range seg*32..seg*32+31
        float4 acc[GTOK];
        #pragma unroll
        for (int g = 0; g < GTOK; ++g) acc[g] = make_float4(0.f, 0.f, 0.f, 0.f);

        #pragma unroll
        for (int i4 = 0; i4 < 8; ++i4) {
            const int d0 = seg * 32 + i4 * 4;
            const float* b2 = vdp + (size_t)d0 * PDIM + pp4 * 4;
            const float4 v0 = *(const float4*)(b2);
            const float4 v1 = *(const float4*)(b2 + PDIM);
            const float4 v2 = *(const float4*)(b2 + 2 * PDIM);
            const float4 v3 = *(const float4*)(b2 + 3 * PDIM);
            const int xoff = d0 + seg;    // d0 + (d0>>5)
            #pragma unroll
            for (int g = 0; g < GTOK; ++g) {
                const float4 xg = *(const float4*)&xs[g * XSS + xoff];
                acc[g].x = fmaf(xg.x, v0.x, acc[g].x);
                acc[g].y = fmaf(xg.x, v0.y, acc[g].y);
                acc[g].z = fmaf(xg.x, v0.z, acc[g].z);
                acc[g].w = fmaf(xg.x, v0.w, acc[g].w);
                acc[g].x = fmaf(xg.y, v1.x, acc[g].x);
                acc[g].y = fmaf(xg.y, v1.y, acc[g].y);
                acc[g].z = fmaf(xg.y, v1.z, acc[g].z);
                acc[g].w = fmaf(xg.y, v1.w, acc[g].w);
                acc[g].x = fmaf(xg.z, v2.x, acc[g].x);
                acc[g].y = fmaf(xg.z, v2.y, acc[g].y);
                acc[g].z = fmaf(xg.z, v2.z, acc[g].z);
                acc[g].w = fmaf(xg.z, v2.w, acc[g].w);
                acc[g].x = fmaf(xg.w, v3.x, acc[g].x);
                acc[g].y = fmaf(xg.w, v3.y, acc[g].y);
                acc[g].z = fmaf(xg.w, v3.z, acc[g].z);
                acc[g].w = fmaf(xg.w, v3.w, acc[g].w);
            }
        }

        // reduce across the 8 segs within each wave (lane bits 3..5)
        #pragma unroll
        for (int g = 0; g < GTOK; ++g) {
            #pragma unroll
            for (int off = 8; off <= 32; off <<= 1) {
                acc[g].x += __shfl_xor(acc[g].x, off, 64);
                acc[g].y += __shfl_xor(acc[g].y, off, 64);
                acc[g].z += __shfl_xor(acc[g].z, off, 64);
                acc[g].w += __shfl_xor(acc[g].w, off, 64);
            }
        }
        const int wv = tid >> 6;
        if ((tid & 0x38) == 0) {          // one lane per (wave, pp4)
            #pragma unroll
            for (int g = 0; g < GTOK; ++g)
                *(float4*)&red[wv][pp4][g * 4] = acc[g];
        }
        __syncthreads();

        // final reduce over 4 waves + silu + weight -> projT[pp][g]
        #pragma unroll
        for (int r = 0; r < 2; ++r) {
            const int idx = tid + r * BLOCK;       // 0..511
            const int pp = idx >> 4, g = idx & 15;
            const int q = pp >> 2, cmp = (g * 4) + (pp & 3);
            const float s = red[0][q][cmp] + red[1][q][cmp]
                          + red[2][q][cmp] + red[3][q][cmp];
            const float pj = s / (1.f + expf(-s)); // silu
            projT[pp][g] = pj * gw[g];
        }
        __syncthreads();

        // ---- phase B: o[g][d] = proj[g] . vu[:,d]
        float4 o[GTOK];
        #pragma unroll
        for (int g = 0; g < GTOK; ++g) o[g] = make_float4(0.f, 0.f, 0.f, 0.f);

        #pragma unroll
        for (int pp = 0; pp < PDIM; ++pp) {
            const float4 vu4 = ((const float4*)(vup + (size_t)pp * DDIM))[tid];
            const float4 pa = *(const float4*)&projT[pp][0];
            const float4 pb = *(const float4*)&projT[pp][4];
            const float4 pc = *(const float4*)&projT[pp][8];
            const float4 pd = *(const float4*)&projT[pp][12];
            o[0].x = fmaf(pa.x, vu4.x, o[0].x); o[0].y = fmaf(pa.x, vu4.y, o[0].y);
            o[0].z = fmaf(pa.x, vu4.z, o[0].z); o[0].w = fmaf(pa.x, vu4.w, o[0].w);
            o[1].x = fmaf(pa.y, vu4.x, o[1].x); o[1].y = fmaf(pa.y, vu4.y, o[1].y);
            o[1].z = fmaf(pa.y, vu4.z, o[1].z); o[1].w = fmaf(pa.y, vu4.w, o[1].w);
            o[2].x = fmaf(pa.z, vu4.x, o[2].x); o[2].y = fmaf(pa.z, vu4.y, o[2].y);
            o[2].z = fmaf(pa.z, vu4.z, o[2].z); o[2].w = fmaf(pa.z, vu4.w, o[2].w);
            o[3].x = fmaf(pa.w, vu4.x, o[3].x); o[3].y = fmaf(pa.w, vu4.y, o[3].y);
            o[3].z = fmaf(pa.w, vu4.z, o[3].z); o[3].w = fmaf(pa.w, vu4.w, o[3].w);
            o[4].x = fmaf(pb.x, vu4.x, o[4].x); o[4].y = fmaf(pb.x, vu4.y, o[4].y);
            o[4].z = fmaf(pb.x, vu4.z, o[4].z); o[4].w = fmaf(pb.x, vu4.w, o[4].w);
            o[5].x = fmaf(pb.y, vu4.x, o[5].x); o[5].y = fmaf(pb.y, vu4.y, o[5].y);
            o[5].z = fmaf(pb.y, vu4.z, o[5].z); o[5].w = fmaf(pb.y, vu4.w, o[5].w);
            o[6].x = fmaf(pb.z, vu4.x, o[6].x); o[6].y = fmaf(pb.z, vu4.y, o[6].y);
            o[6].z = fmaf(pb.z, vu4.z, o[6].z); o[6].w = fmaf(pb.z, vu4.w, o[6].w);
            o[7].x = fmaf(pb.w, vu4.x, o[7].x); o[7].y = fmaf(pb.w, vu4.y, o[7].y);
            o[7].z = fmaf(pb.w, vu4.z, o[7].z); o[7].w = fmaf(pb.w, vu4.w, o[7].w);
            o[8].x = fmaf(pc.x, vu4.x, o[8].x); o[8].y = fmaf(pc.x, vu4.y, o[8].y);
            o[8].z = fmaf(pc.x, vu4.z, o[8].z); o[8].w = fmaf(pc.x, vu4.w, o[8].w);
            o[9].x = fmaf(pc.y, vu4.x, o[9].x); o[9].y = fmaf(pc.y, vu4.y, o[9].y);
            o[9].z = fmaf(pc.y, vu4.z, o[9].z); o[9].w = fmaf(pc.y, vu4.w, o[9].w);
            o[10].x = fmaf(pc.z, vu4.x, o[10].x); o[10].y = fmaf(pc.z, vu4.y, o[10].y);
            o[10].z = fmaf(pc.z, vu4.z, o[10].z); o[10].w = fmaf(pc.z, vu4.w, o[10].w);
            o[11].x = fmaf(pc.w, vu4.x, o[11].x); o[11].y = fmaf(pc.w, vu4.y, o[11].y);
            o[11].z = fmaf(pc.w, vu4.z, o[11].z); o[11].w = fmaf(pc.w, vu4.w, o[11].w);
            o[12].x = fmaf(pd.x, vu4.x, o[12].x); o[12].y = fmaf(pd.x, vu4.y, o[12].y);
            o[12].z = fmaf(pd.x, vu4.z, o[12].z); o[12].w = fmaf(pd.x, vu4.w, o[12].w);
            o[13].x = fmaf(pd.y, vu4.x, o[13].x); o[13].y = fmaf(pd.y, vu4.y, o[13].y);
            o[13].z = fmaf(pd.y, vu4.z, o[13].z); o[13].w = fmaf(pd.y, vu4.w, o[13].w);
            o[14].x = fmaf(pd.z, vu4.x, o[14].x); o[14].y = fmaf(pd.z, vu4.y, o[14].y);
            o[14].z = fmaf(pd.z, vu4.z, o[14].z); o[14].w = fmaf(pd.z, vu4.w, o[14].w);
            o[15].x = fmaf(pd.w, vu4.x, o[15].x); o[15].y = fmaf(pd.w, vu4.y, o[15].y);
            o[15].z = fmaf(pd.w, vu4.z, o[15].z); o[15].w = fmaf(pd.w, vu4.w, o[15].w);
        }

        if (MODE == 0) {
            #pragma unroll
            for (int g = 0; g < GTOK; ++g)
                ((float4*)(dst + (size_t)gs[g] * DDIM))[tid] = o[g];
        } else {
            #pragma unroll
            for (int g = 0; g < GTOK; ++g) {
                if (g < gv) {
                    float* op = dst + (size_t)gt[g] * DDIM + tid * 4;
                    atomicAdd(op + 0, o[g].x);
                    atomicAdd(op + 1, o[g].y);
                    atomicAdd(op + 2, o[g].z);
                    atomicAdd(op + 3, o[g].w);
                }
            }
        }
        __syncthreads();   // LDS reused next group
    }
}

// ---------------------------------------------------------------------------
// K4: out[t] = x[t] + sum_k contrib[slot_of[t][k]]  (weights already applied)
__global__ __launch_bounds__(BLOCK) void combine_kernel(
    const float* __restrict__ x, const float* __restrict__ contrib,
    const int* __restrict__ slotof, float* __restrict__ out)
{
    __shared__ int sl[TOPK];
    const int t = blockIdx.x, tid = threadIdx.x;
    if (tid < TOPK) sl[tid] = slotof[t * TOPK + tid];
    __syncthreads();
    float4 r = ((const float4*)(x + (size_t)t * DDIM))[tid];
    #pragma unroll
    for (int k = 0; k < TOPK; ++k) {
        const float4 cv = ((const float4*)(contrib + (size_t)sl[k] * DDIM))[tid];
        r.x += cv.x; r.y += cv.y; r.z += cv.z; r.w += cv.w;
    }
    ((float4*)(out + (size_t)t * DDIM))[tid] = r;
}

// ---------------------------------------------------------------------------
extern "C" void kernel_launch(void* const* d_in, const int* in_sizes, int n_in,
                              void* d_out, int out_size, void* d_ws, size_t ws_size,
                              hipStream_t stream) {
    const float* x        = (const float*)d_in[0];
    const float* hasher_w = (const float*)d_in[1];
    const float* keys     = (const float*)d_in[2];
    const float* vd       = (const float*)d_in[3];
    const float* vu       = (const float*)d_in[4];
    const float* scale    = (const float*)d_in[5];
    float* out = (float*)d_out;

    const int ntok = in_sizes[0] / DDIM;        // B*T
    const int nent = ntok * TOPK;

    // workspace layout
    char* w = (char*)d_ws;
    const size_t o_cnt  = 0;                    // 256 int
    const size_t o_offs = 1024;                 // 257 int
    const size_t o_cur  = 2560;                 // 256 int
    const size_t o_tki  = 4096;                                   // nent int
    const size_t o_tkw  = o_tki  + (size_t)nent * 4;              // nent float
    const size_t o_etok = o_tkw  + (size_t)nent * 4;              // nent int
    const size_t o_ew   = o_etok + (size_t)nent * 4;              // nent float
    const size_t o_slot = o_ew   + (size_t)nent * 4;              // nent int
    const size_t o_ctb  = (o_slot + (size_t)nent * 4 + 255) & ~(size_t)255;
    const size_t needA  = o_ctb + (size_t)(nent + 1) * DDIM * 4;  // +1 dummy row
    const size_t needB  = o_slot + (size_t)nent * 4;

    int*   cnt    = (int*)(w + o_cnt);
    int*   offs   = (int*)(w + o_offs);
    int*   cursor = (int*)(w + o_cur);
    int*   tki    = (int*)(w + o_tki);
    float* tkw    = (float*)(w + o_tkw);
    int*   etok   = (int*)(w + o_etok);
    float* ew     = (float*)(w + o_ew);
    int*   slotof = (int*)(w + o_slot);
    float* contrib= (float*)(w + o_ctb);

    // shared front-end: route -> scan -> fill
    hipLaunchKernelGGL(zero_cnt_kernel, dim3(1), dim3(NPAT), 0, stream, cnt);
    hipLaunchKernelGGL(route_kernel, dim3(ntok), dim3(BLOCK), 0, stream,
                       x, hasher_w, keys, tki, tkw, cnt);
    hipLaunchKernelGGL(scan_kernel, dim3(1), dim3(NPAT), 0, stream,
                       cnt, offs, cursor);
    hipLaunchKernelGGL(fill_kernel, dim3((nent + BLOCK - 1) / BLOCK), dim3(BLOCK),
                       0, stream, tki, tkw, scale, cursor, etok, ew, slotof, nent);

    if (ws_size >= needA) {
        hipLaunchKernelGGL((pattern_gemm_kernel<0>), dim3(NPAT * CHUNKS), dim3(BLOCK),
                           0, stream, x, vd, vu, offs, etok, ew, contrib, nent);
        hipLaunchKernelGGL(combine_kernel, dim3(ntok), dim3(BLOCK), 0, stream,
                           x, contrib, slotof, out);
    } else if (ws_size >= needB) {
        // atomic fallback: out = x, then atomicAdd weighted contributions
        hipMemcpyAsync(out, x, (size_t)ntok * DDIM * 4, hipMemcpyDeviceToDevice,
                       stream);
        hipLaunchKernelGGL((pattern_gemm_kernel<1>), dim3(NPAT * CHUNKS), dim3(BLOCK),
                           0, stream, x, vd, vu, offs, etok, ew, out, nent);
    }
    // (ws_size smaller than ~170 KB is not expected for this problem)
}